// Round 9
// baseline (568.396 us; speedup 1.0000x reference)
//
#include <hip/hip_runtime.h>

typedef short v8s __attribute__((ext_vector_type(8)));   // 8 x bf16 (4 VGPR)
typedef float v4f __attribute__((ext_vector_type(4)));
typedef float v2f __attribute__((ext_vector_type(2)));

// HW packed f32->bf16 (RNE), 2 elems/instr. No builtin on gfx950 -> inline asm.
__device__ __forceinline__ unsigned cvtpk(float lo, float hi) {
    unsigned r;
    asm("v_cvt_pk_bf16_f32 %0, %1, %2" : "=v"(r) : "v"(lo), "v"(hi));
    return r;
}
// Packed dual-f32 VOP3P (CDNA2+; hipcc never auto-forms these from scalar f32).
__device__ __forceinline__ v2f pk_mul(v2f a, v2f b) {
    v2f r; asm("v_pk_mul_f32 %0, %1, %2" : "=v"(r) : "v"(a), "v"(b)); return r;
}
__device__ __forceinline__ v2f pk_add(v2f a, v2f b) {
    v2f r; asm("v_pk_add_f32 %0, %1, %2" : "=v"(r) : "v"(a), "v"(b)); return r;
}
__device__ __forceinline__ v2f pk_fma(v2f a, v2f b, v2f c) {
    v2f r; asm("v_pk_fma_f32 %0, %1, %2, %3" : "=v"(r) : "v"(a), "v"(b), "v"(c)); return r;
}
__device__ __forceinline__ v8s pack8(float4 f0, float4 f1) {
    union { unsigned u[4]; v8s v; } r;
    r.u[0] = cvtpk(f0.x, f0.y); r.u[1] = cvtpk(f0.z, f0.w);
    r.u[2] = cvtpk(f1.x, f1.y); r.u[3] = cvtpk(f1.z, f1.w);
    return r.v;
}
__device__ __forceinline__ v4f mfma(v8s a, v8s b, v4f c) {
    return __builtin_amdgcn_mfma_f32_16x16x32_bf16(a, b, c, 0, 0, 0);
}
// B-frag for Z = Xin @ W^T from f32 W: lane holds W[n][k0..k0+7] as bf16.
__device__ __forceinline__ v8s ldwf(const float* W, int rowElems, int n, int k0) {
    const float* p = W + (size_t)n * rowElems + k0;
    union { unsigned u[4]; v8s v; } r;
    #pragma unroll
    for (int j = 0; j < 4; ++j) r.u[j] = cvtpk(p[2 * j], p[2 * j + 1]);
    return r.v;
}

// Fused-denominator LSTM cell, PACKED: 2 cells per call. Same dataflow as the
// scalar cell (verified R3-R8, absmax 0.015625); muls/adds/fma run as VOP3P
// dual-f32 (2 lanes/issue), trans (exp2/rcp) stay scalar per component.
__device__ __forceinline__ v2f cell2(v2f zi, v2f zf, v2f zg, v2f zo, v2f& c) {
    const v2f NL = {-1.44269504f, -1.44269504f};
    const v2f PG = { 2.88539008f,  2.88539008f};
    const v2f ONE = {1.f, 1.f};
    const v2f M1  = {-1.f, -1.f};
    v2f ti = pk_mul(NL, zi), tf = pk_mul(NL, zf), tg = pk_mul(PG, zg), to = pk_mul(NL, zo);
    v2f ei, ef, eg, eo;
    ei[0] = __builtin_amdgcn_exp2f(ti[0]); ei[1] = __builtin_amdgcn_exp2f(ti[1]);
    ef[0] = __builtin_amdgcn_exp2f(tf[0]); ef[1] = __builtin_amdgcn_exp2f(tf[1]);
    eg[0] = __builtin_amdgcn_exp2f(tg[0]); eg[1] = __builtin_amdgcn_exp2f(tg[1]);
    eo[0] = __builtin_amdgcn_exp2f(to[0]); eo[1] = __builtin_amdgcn_exp2f(to[1]);
    v2f Df  = pk_add(ONE, ef);
    v2f Dig = pk_mul(pk_add(ONE, ei), pk_add(ONE, eg));
    v2f num = pk_fma(c, Dig, pk_mul(Df, pk_add(eg, M1)));
    v2f den = pk_mul(Df, Dig);
    v2f rc; rc[0] = __builtin_amdgcn_rcpf(den[0]); rc[1] = __builtin_amdgcn_rcpf(den[1]);
    v2f cc = pk_mul(num, rc);
    c = cc;
    v2f tc = pk_mul(PG, cc);
    tc[0] = fminf(tc[0], 60.f); tc[1] = fminf(tc[1], 60.f);   // lossless clamp
    v2f ec;
    ec[0] = __builtin_amdgcn_exp2f(tc[0]); ec[1] = __builtin_amdgcn_exp2f(tc[1]);
    v2f dh = pk_mul(pk_add(ONE, eo), pk_add(ONE, ec));
    v2f rh; rh[0] = __builtin_amdgcn_rcpf(dh[0]); rh[1] = __builtin_amdgcn_rcpf(dh[1]);
    return pk_mul(pk_add(ec, M1), rh);
}
__device__ __forceinline__ v2f lo2(v4f a) { return (v2f){a[0], a[1]}; }
__device__ __forceinline__ v2f hi2(v4f a) { return (v2f){a[2], a[3]}; }
// cells for one acc set (4 gates x 4 q) -> two packed bf16 words
__device__ __forceinline__ void cells_pk(const v4f* acc, v2f* cst, unsigned& p0, unsigned& p1) {
    v2f h0 = cell2(lo2(acc[0]), lo2(acc[1]), lo2(acc[2]), lo2(acc[3]), cst[0]);
    v2f h1 = cell2(hi2(acc[0]), hi2(acc[1]), hi2(acc[2]), hi2(acc[3]), cst[1]);
    p0 = cvtpk(h0[0], h0[1]);
    p1 = cvtpk(h1[0], h1[1]);
}

// Occupancy is structurally 2 waves/SIMD (R1/R5/R6/R7: every >2-wave attempt
// spills). R8 structure kept: enc = ONE phase/step (l1(t) + pipelined l0(t+1)),
// dec = 2 barriers/step with hoisted Whh1-half and pipelined l0(s+1)/GEMM2.
__global__ __launch_bounds__(256, 2) void seq2seq(
    const float* __restrict__ X,
    const float* __restrict__ bias,
    const float* __restrict__ eWih0, const float* __restrict__ eWhh0, const float* __restrict__ eb0,
    const float* __restrict__ eWih1, const float* __restrict__ eWhh1, const float* __restrict__ eb1,
    const float* __restrict__ dWih0, const float* __restrict__ dWhh0, const float* __restrict__ db0,
    const float* __restrict__ dWih1, const float* __restrict__ dWhh1, const float* __restrict__ db1,
    const float* __restrict__ rW1, const float* __restrict__ rb1,
    const float* __restrict__ rW2, const float* __restrict__ rb2,
    float* __restrict__ out)
{
    __shared__ __align__(16) short sh0[2][1024];
    __shared__ __align__(16) short sh1[2][1024];
    __shared__ __align__(16) short sy1[1024];

    const int tid  = threadIdx.x;
    const int lane = tid & 63;
    const int w    = tid >> 6;            // unit-group 0..3 (units 16w..16w+15)
    const int lo   = lane & 15, hi = lane >> 4;
    const int wg   = blockIdx.x;          // 16 batch rows per block

    // zero sh1 slot 1 (= h1(-1)); sh0 needs no zeroing (prologue writes h0(0))
    for (int i = tid; i < 512; i += 256) ((int*)sh1)[512 + i] = 0;

    const int wsidx = (w >> 1) * 512 + (((2 * w) + (lo >> 3)) & 3) * 128 + hi * 32 + (lo & 7);

    // ---- encoder weights -> register B-frags ----
    v8s wx[4], wh[4][2], wi1[4][2], wh1[4][2];
    float bz0[4], bz1[4];
    #pragma unroll
    for (int g = 0; g < 4; ++g) {
        const int n = (w + 4 * g) * 16 + lo;
        v8s z = {0, 0, 0, 0, 0, 0, 0, 0};
        wx[g] = (hi < 2) ? ldwf(eWih0, 16, n, (hi & 1) * 8) : z;   // K=16 zero-pad
        #pragma unroll
        for (int kk = 0; kk < 2; ++kk) {
            wh[g][kk]  = ldwf(eWhh0, 64, n, kk * 32 + hi * 8);
            wi1[g][kk] = ldwf(eWih1, 64, n, kk * 32 + hi * 8);
            wh1[g][kk] = ldwf(eWhh1, 64, n, kk * 32 + hi * 8);
        }
        bz0[g] = eb0[g * 64 + w * 16 + lo];
        bz1[g] = eb1[g * 64 + w * 16 + lo];
    }

    v2f c0[2] = {{0.f, 0.f}, {0.f, 0.f}};
    v2f c1[2] = {{0.f, 0.f}, {0.f, 0.f}};

    const float* xb = X + (size_t)(wg * 16 + lo) * 1536 + (hi & 1) * 8;

    // ---- enc prologue: h0(0) = cell(b0 + x(0)@Wih0^T)
    v4f acc0[4];
    {
        const v8s ax = pack8(*(const float4*)xb, *(const float4*)(xb + 4));
        #pragma unroll
        for (int g = 0; g < 4; ++g) {
            acc0[g] = (v4f){bz0[g], bz0[g], bz0[g], bz0[g]};
            acc0[g] = mfma(ax, wx[g], acc0[g]);
        }
        unsigned p0, p1;
        cells_pk(acc0, c0, p0, p1);
        short* b = &sh0[0][wsidx];
        b[0] = (short)p0; b[8] = (short)(p0 >> 16);
        b[16] = (short)p1; b[24] = (short)(p1 >> 16);
    }
    __syncthreads();   // h0(0) + sh1 zeros visible

    // ================= encoder: ONE phase + ONE barrier per step ==============
    // phase(t): reads h0(t) [sh0[sA]] + h1(t-1) [sh1[sB]]; computes l1(t) AND
    // the pipelined l0(t+1); writes h1(t) -> sh1[sA], h0(t+1) -> sh0[sB].
    #pragma unroll 2
    for (int t = 0; t < 96; ++t) {
        const int sA = t & 1, sB = sA ^ 1;
        const int tn = (t < 95) ? t + 1 : 95;       // clamp: t=95 result discarded
        const float* p = xb + tn * 16;
        const float4 xv0 = *(const float4*)p;
        const float4 xv1 = *(const float4*)(p + 4);
        v8s ah[2], bh[2];
        #pragma unroll
        for (int kk = 0; kk < 2; ++kk) {
            ah[kk] = *(const v8s*)&sh0[sA][kk * 512 + lane * 8];   // h0(t)
            bh[kk] = *(const v8s*)&sh1[sB][kk * 512 + lane * 8];   // h1(t-1)
        }
        // l1(t): 16 MFMA
        v4f acc1[4];
        #pragma unroll
        for (int g = 0; g < 4; ++g)
            acc1[g] = (v4f){bz1[g], bz1[g], bz1[g], bz1[g]};
        #pragma unroll
        for (int kk = 0; kk < 2; ++kk)
            #pragma unroll
            for (int g = 0; g < 4; ++g) {
                acc1[g] = mfma(ah[kk], wi1[g][kk], acc1[g]);
                acc1[g] = mfma(bh[kk], wh1[g][kk], acc1[g]);
            }
        // l0(t+1): 12 MFMA (reuses ah)
        #pragma unroll
        for (int g = 0; g < 4; ++g)
            acc0[g] = (v4f){bz0[g], bz0[g], bz0[g], bz0[g]};
        #pragma unroll
        for (int kk = 0; kk < 2; ++kk)
            #pragma unroll
            for (int g = 0; g < 4; ++g) acc0[g] = mfma(ah[kk], wh[g][kk], acc0[g]);
        {
            const v8s ax = pack8(xv0, xv1);
            #pragma unroll
            for (int g = 0; g < 4; ++g) acc0[g] = mfma(ax, wx[g], acc0[g]);
        }
        // cells1 -> h1(t) -> sh1[sA]
        {
            unsigned p0, p1;
            cells_pk(acc1, c1, p0, p1);
            short* b = &sh1[sA][wsidx];
            b[0] = (short)p0; b[8] = (short)(p0 >> 16);
            b[16] = (short)p1; b[24] = (short)(p1 >> 16);
        }
        // cells0 -> h0(t+1) -> sh0[sB]  (independent chain: ILP with cells1)
        {
            unsigned p0, p1;
            cells_pk(acc0, c0, p0, p1);
            short* b = &sh0[sB][wsidx];
            b[0] = (short)p0; b[8] = (short)(p0 >> 16);
            b[16] = (short)p1; b[24] = (short)(p1 >> 16);
        }
        __syncthreads();
    }
    // finals: h0(95) in sh0[1], h1(95) in sh1[1].

    // ---- decoder + head weights -> registers ----
    v8s dX0[4][2], dH0[4][2], dX1[4][2], dH1[4][2];
    #pragma unroll
    for (int g = 0; g < 4; ++g) {
        const int n = (w + 4 * g) * 16 + lo;
        #pragma unroll
        for (int kk = 0; kk < 2; ++kk) {
            dX0[g][kk] = ldwf(dWih0, 64, n, kk * 32 + hi * 8);
            dH0[g][kk] = ldwf(dWhh0, 64, n, kk * 32 + hi * 8);
            dX1[g][kk] = ldwf(dWih1, 64, n, kk * 32 + hi * 8);
            dH1[g][kk] = ldwf(dWhh1, 64, n, kk * 32 + hi * 8);
        }
        bz0[g] = db0[g * 64 + w * 16 + lo];
        bz1[g] = db1[g * 64 + w * 16 + lo];
    }
    v8s w1f[2], w2f[2];
    #pragma unroll
    for (int kk = 0; kk < 2; ++kk) {
        w1f[kk] = ldwf(rW1, 64, w * 16 + lo, kk * 32 + hi * 8);
        w2f[kk] = ldwf(rW2, 64, lo, kk * 32 + hi * 8);
    }
    const float hb1 = rb1[w * 16 + lo];
    const float hb2 = rb2[lo];
    float lb[4];
    #pragma unroll
    for (int q = 0; q < 4; ++q)
        lb[q] = bias[(size_t)(wg * 16 + hi * 4 + q) * 16 + lo];
    c0[0] = (v2f){0.f, 0.f}; c0[1] = (v2f){0.f, 0.f};
    c1[0] = (v2f){0.f, 0.f}; c1[1] = (v2f){0.f, 0.f};

    // ---- dec prologue: acc0 = full l0(0) preactivation from encoder finals
    {
        v8s ah[2], bh[2];
        #pragma unroll
        for (int kk = 0; kk < 2; ++kk) {
            ah[kk] = *(const v8s*)&sh1[1][kk * 512 + lane * 8];   // h_t = h1(95)
            bh[kk] = *(const v8s*)&sh0[1][kk * 512 + lane * 8];   // dh0 = h0(95)
        }
        #pragma unroll
        for (int g = 0; g < 4; ++g)
            acc0[g] = (v4f){bz0[g], bz0[g], bz0[g], bz0[g]};
        #pragma unroll
        for (int kk = 0; kk < 2; ++kk)
            #pragma unroll
            for (int g = 0; g < 4; ++g) {
                acc0[g] = mfma(ah[kk], dX0[g][kk], acc0[g]);
                acc0[g] = mfma(bh[kk], dH0[g][kk], acc0[g]);
            }
    }

    // ============ decoder: A bar1 [GEMM2 | l1] bar2 C(GEMM1 + l0(s+1)) ========
    #pragma unroll 2
    for (int s = 0; s < 24; ++s) {
        const int pw = s & 1, pr = pw ^ 1;
        // ---- A(s): hoisted Whh1*h1(s-1) + cells0 + write h0
        v4f acc1[4];
        {
            v8s bh[2];
            #pragma unroll
            for (int kk = 0; kk < 2; ++kk)
                bh[kk] = *(const v8s*)&sh1[pr][kk * 512 + lane * 8];   // h1(s-1)
            #pragma unroll
            for (int g = 0; g < 4; ++g)
                acc1[g] = (v4f){bz1[g], bz1[g], bz1[g], bz1[g]};
            #pragma unroll
            for (int kk = 0; kk < 2; ++kk)
                #pragma unroll
                for (int g = 0; g < 4; ++g)
                    acc1[g] = mfma(bh[kk], dH1[g][kk], acc1[g]);
        }
        {
            unsigned p0, p1;
            cells_pk(acc0, c0, p0, p1);
            short* b = &sh0[pw][wsidx];
            b[0] = (short)p0; b[8] = (short)(p0 >> 16);
            b[16] = (short)p1; b[24] = (short)(p1 >> 16);
        }
        __syncthreads();                      // bar1: h0(s) ready; sy1(s-1) readable
        // ---- head GEMM2 for step s-1 (wave 0 only), overlaps l1 of other waves
        if (w == 0 && s > 0) {
            v4f a2 = (v4f){hb2, hb2, hb2, hb2};
            #pragma unroll
            for (int kk = 0; kk < 2; ++kk) {
                const v8s a = *(const v8s*)&sy1[kk * 512 + lane * 8];
                a2 = mfma(a, w2f[kk], a2);
            }
            #pragma unroll
            for (int q = 0; q < 4; ++q) {
                size_t row = (size_t)(wg * 16 + hi * 4 + q);
                out[row * 384 + (s - 1) * 16 + lo] = a2[q] + lb[q];
            }
        }
        // ---- l1(s): remaining 8 MFMA + cells1 + write h1
        {
            v8s ah[2];
            #pragma unroll
            for (int kk = 0; kk < 2; ++kk)
                ah[kk] = *(const v8s*)&sh0[pw][kk * 512 + lane * 8];   // h0(s)
            #pragma unroll
            for (int kk = 0; kk < 2; ++kk)
                #pragma unroll
                for (int g = 0; g < 4; ++g)
                    acc1[g] = mfma(ah[kk], dX1[g][kk], acc1[g]);
            unsigned p0, p1;
            cells_pk(acc1, c1, p0, p1);
            short* b = &sh1[pw][wsidx];
            b[0] = (short)p0; b[8] = (short)(p0 >> 16);
            b[16] = (short)p1; b[24] = (short)(p1 >> 16);
        }
        __syncthreads();                      // bar2: h1(s) ready
        // ---- C(s): GEMM1 + sy1 write + pipelined l0(s+1)
        {
            v8s h1f[2], h0f[2];
            #pragma unroll
            for (int kk = 0; kk < 2; ++kk) {
                h1f[kk] = *(const v8s*)&sh1[pw][kk * 512 + lane * 8];   // h1(s)
                h0f[kk] = *(const v8s*)&sh0[pw][kk * 512 + lane * 8];   // h0(s)
            }
            v4f ay = (v4f){hb1, hb1, hb1, hb1};
            #pragma unroll
            for (int kk = 0; kk < 2; ++kk) ay = mfma(h1f[kk], w1f[kk], ay);
            #pragma unroll
            for (int qp = 0; qp < 2; ++qp) {
                unsigned pk = cvtpk(fmaxf(ay[2 * qp], 0.f), fmaxf(ay[2 * qp + 1], 0.f));
                short* b = &sy1[wsidx + qp * 16];
                b[0] = (short)pk; b[8] = (short)(pk >> 16);
            }
            // l0(s+1): 16 MFMA (s=23's result discarded)
            #pragma unroll
            for (int g = 0; g < 4; ++g)
                acc0[g] = (v4f){bz0[g], bz0[g], bz0[g], bz0[g]};
            #pragma unroll
            for (int kk = 0; kk < 2; ++kk)
                #pragma unroll
                for (int g = 0; g < 4; ++g) {
                    acc0[g] = mfma(h1f[kk], dX0[g][kk], acc0[g]);
                    acc0[g] = mfma(h0f[kk], dH0[g][kk], acc0[g]);
                }
        }
    }
    // ---- drain: head GEMM2 for s=23 ----
    __syncthreads();
    if (w == 0) {
        v4f a2 = (v4f){hb2, hb2, hb2, hb2};
        #pragma unroll
        for (int kk = 0; kk < 2; ++kk) {
            const v8s a = *(const v8s*)&sy1[kk * 512 + lane * 8];
            a2 = mfma(a, w2f[kk], a2);
        }
        #pragma unroll
        for (int q = 0; q < 4; ++q) {
            size_t row = (size_t)(wg * 16 + hi * 4 + q);
            out[row * 384 + 23 * 16 + lo] = a2[q] + lb[q];
        }
    }
}

extern "C" void kernel_launch(void* const* d_in, const int* in_sizes, int n_in,
                              void* d_out, int out_size, void* d_ws, size_t ws_size,
                              hipStream_t stream) {
    seq2seq<<<dim3(1024), dim3(256), 0, stream>>>(
        (const float*)d_in[0],   // X
        (const float*)d_in[1],   // bias   (d_in[2] = X_mask, unused by reference)
        (const float*)d_in[3],  (const float*)d_in[4],  (const float*)d_in[5],
        (const float*)d_in[6],  (const float*)d_in[7],  (const float*)d_in[8],
        (const float*)d_in[9],  (const float*)d_in[10], (const float*)d_in[11],
        (const float*)d_in[12], (const float*)d_in[13], (const float*)d_in[14],
        (const float*)d_in[15], (const float*)d_in[16],
        (const float*)d_in[17], (const float*)d_in[18],
        (float*)d_out);
}